// Round 3
// baseline (1339.132 us; speedup 1.0000x reference)
//
#include <hip/hip_runtime.h>
#include <hip/hip_bf16.h>
#include <math.h>

#define N_NODES 20000
#define E2      240000     // directed edges (2E)
#define EP      120000     // positive edges
#define ENEG    600000     // negative edges
#define ETOT    720000     // EP + ENEG

typedef __attribute__((ext_vector_type(8))) short bf16x8;
typedef __attribute__((ext_vector_type(4))) float f32x4;

__device__ __forceinline__ float logsigf(float x) {
    // log_sigmoid(x) = min(x,0) - log1p(exp(-|x|))
    return fminf(x, 0.0f) - log1pf(expf(-fabsf(x)));
}

__device__ __forceinline__ unsigned short f2bf(float f) {
    unsigned u = __float_as_uint(f);
    u += 0x7FFF + ((u >> 16) & 1);   // RNE
    return (unsigned short)(u >> 16);
}

// ---------------- K1: m1 = x @ W1   [20000,256] @ [256,256] ----------------
__global__ __launch_bounds__(256) void k_mm_xW1(const float* __restrict__ x,
                                                const float* __restrict__ W1,
                                                float* __restrict__ m1) {
    __shared__ float xl[8 * 256];
    const int tid = threadIdx.x;
    const long base = (long)blockIdx.x * 8 * 256;
    const float4* src = (const float4*)(x + base);
    float4* dst = (float4*)xl;
    for (int i = tid; i < 512; i += 256) dst[i] = src[i];
    __syncthreads();
    float acc[8] = {0.f,0.f,0.f,0.f,0.f,0.f,0.f,0.f};
    for (int k = 0; k < 256; k += 4) {
        const float w0 = W1[(k + 0) * 256 + tid];
        const float w1 = W1[(k + 1) * 256 + tid];
        const float w2 = W1[(k + 2) * 256 + tid];
        const float w3 = W1[(k + 3) * 256 + tid];
#pragma unroll
        for (int r = 0; r < 8; ++r) {
            const float4 xv = *(const float4*)&xl[r * 256 + k];
            acc[r] += xv.x * w0 + xv.y * w1 + xv.z * w2 + xv.w * w3;
        }
    }
#pragma unroll
    for (int r = 0; r < 8; ++r) m1[base + r * 256 + tid] = acc[r];
}

// ------- K2/K4: scatter-add rows (dim 256), atomics; 8 edges per block -------
__global__ __launch_bounds__(256) void k_scatter256(const float* __restrict__ feat,
                                                    float* __restrict__ out,
                                                    const int* __restrict__ srcs,
                                                    const int* __restrict__ dsts) {
    const int t = threadIdx.x;
    const int e0 = blockIdx.x * 8;
#pragma unroll
    for (int k = 0; k < 8; ++k) {
        const int s = srcs[e0 + k], d = dsts[e0 + k];
        atomicAdd(&out[(long)d * 256 + t], feat[(long)s * 256 + t]);
    }
}

// ---------------- K3: h1 = relu(LN(h1pre + b1)) in place ----------------
__global__ __launch_bounds__(256) void k_ln_relu(float* __restrict__ h,
                                                 const float* __restrict__ b1,
                                                 const float* __restrict__ g1,
                                                 const float* __restrict__ bt1) {
    const int w = threadIdx.x >> 6;
    const int lane = threadIdx.x & 63;
    const long row = (long)blockIdx.x * 4 + w;
    float4 v = *(const float4*)(h + row * 256 + lane * 4);
    const float4 b = *(const float4*)(b1 + lane * 4);
    v.x += b.x; v.y += b.y; v.z += b.z; v.w += b.w;
    float s  = v.x + v.y + v.z + v.w;
    float sq = v.x * v.x + v.y * v.y + v.z * v.z + v.w * v.w;
    for (int o = 32; o > 0; o >>= 1) {
        s  += __shfl_xor(s, o, 64);
        sq += __shfl_xor(sq, o, 64);
    }
    const float mean = s * (1.0f / 256.0f);
    const float var  = sq * (1.0f / 256.0f) - mean * mean;
    const float rs = rsqrtf(var + 1e-5f);
    const float4 g  = *(const float4*)(g1 + lane * 4);
    const float4 bt = *(const float4*)(bt1 + lane * 4);
    float4 o4;
    o4.x = fmaxf((v.x - mean) * rs * g.x + bt.x, 0.f);
    o4.y = fmaxf((v.y - mean) * rs * g.y + bt.y, 0.f);
    o4.z = fmaxf((v.z - mean) * rs * g.z + bt.z, 0.f);
    o4.w = fmaxf((v.w - mean) * rs * g.w + bt.w, 0.f);
    *(float4*)(h + row * 256 + lane * 4) = o4;
}

// ------- K5: mu/logvar from agg1, z = mu + eps*exp(lv/2), kl partial -------
__global__ __launch_bounds__(256) void k_mulv(const float* __restrict__ agg1,
                                              const float* __restrict__ Wmu,
                                              const float* __restrict__ bmu,
                                              const float* __restrict__ Wlv,
                                              const float* __restrict__ blv,
                                              const float* __restrict__ eps,
                                              float* __restrict__ z,
                                              double* __restrict__ kl_accum) {
    __shared__ float rows[4 * 256];
    const int tid = threadIdx.x;
    const long base = (long)blockIdx.x * 4 * 256;
    ((float4*)rows)[tid] = ((const float4*)(agg1 + base))[tid];
    __syncthreads();
    const int r = tid >> 6;
    const int c = tid & 63;
    float amu = 0.f, alv = 0.f;
    for (int k = 0; k < 256; k += 4) {
        const float4 a = *(const float4*)&rows[r * 256 + k];
        amu += a.x * Wmu[(k+0)*64+c] + a.y * Wmu[(k+1)*64+c]
             + a.z * Wmu[(k+2)*64+c] + a.w * Wmu[(k+3)*64+c];
        alv += a.x * Wlv[(k+0)*64+c] + a.y * Wlv[(k+1)*64+c]
             + a.z * Wlv[(k+2)*64+c] + a.w * Wlv[(k+3)*64+c];
    }
    const float mu = amu + bmu[c];
    const float lv = alv + blv[c];
    const long i = (long)blockIdx.x * 4 + r;
    const float ev = eps[i * 64 + c];
    z[i * 64 + c] = mu + ev * expf(0.5f * lv);
    float term = 1.0f + lv - mu * mu - expf(lv);
    for (int o = 32; o > 0; o >>= 1) term += __shfl_xor(term, o, 64);
    if (c == 0) atomicAdd(kl_accum, (double)term);
}

// ---------------- K6: degree count, then dis = rsqrt(deg+1) ----------------
__global__ void k_deg(const int* __restrict__ pd, float* __restrict__ deg) {
    const int e = blockIdx.x * 256 + threadIdx.x;
    if (e < EP) atomicAdd(&deg[pd[e]], 1.0f);
}
__global__ void k_dis(float* __restrict__ deg_dis) {
    const int i = blockIdx.x * 256 + threadIdx.x;
    if (i < N_NODES) deg_dis[i] = rsqrtf(fmaxf(deg_dis[i] + 1.0f, 1.0f));
}

// -- K7a/K8a: normalized scatter (dim 64) over positive edges; 16/block --
__global__ __launch_bounds__(256) void k_scatter_norm64(const float* __restrict__ feat,
                                                        float* __restrict__ out,
                                                        const int* __restrict__ ps,
                                                        const int* __restrict__ pd,
                                                        const float* __restrict__ dis) {
    const int t = threadIdx.x & 63;
    const int e0 = blockIdx.x * 16 + (threadIdx.x >> 6) * 4;
#pragma unroll
    for (int k = 0; k < 4; ++k) {
        const int e = e0 + k;
        const int s = ps[e], d = pd[e];
        const float w = dis[s] * dis[d];
        atomicAdd(&out[(long)d * 64 + t], feat[(long)s * 64 + t] * w);
    }
}

// --- K7b: hdec = relu((agg + self*dis^2) @ Wd + bd), fp32 out ---
__global__ __launch_bounds__(256) void k_dec_mm(const float* __restrict__ agg,
                                                const float* __restrict__ self_feat,
                                                const float* __restrict__ dis,
                                                const float* __restrict__ Wd,
                                                const float* __restrict__ bd,
                                                float* __restrict__ out) {
    __shared__ float rows[4 * 64];
    __shared__ float sW[64 * 64];
    const int tid = threadIdx.x;
    {
        const float4* w4 = (const float4*)Wd;
        float4* sw4 = (float4*)sW;
        for (int i = tid; i < 1024; i += 256) sw4[i] = w4[i];
    }
    const int r = tid >> 6, c = tid & 63;
    const long i = (long)blockIdx.x * 4 + r;
    const float dsi = dis[i];
    rows[r * 64 + c] = agg[i * 64 + c] + self_feat[i * 64 + c] * dsi * dsi;
    __syncthreads();
    float acc = 0.f;
    for (int k = 0; k < 64; k += 4) {
        const float4 a = *(const float4*)&rows[r * 64 + k];
        acc += a.x * sW[(k+0)*64+c] + a.y * sW[(k+1)*64+c]
             + a.z * sW[(k+2)*64+c] + a.w * sW[(k+3)*64+c];
    }
    out[i * 64 + c] = fmaxf(acc + bd[c], 0.f);
}

// --- K8b: h2bf = bf16(relu((agg + self*dis^2) @ Wd + bd)) — edge-MLP input ---
__global__ __launch_bounds__(256) void k_dec_mm_bf16(const float* __restrict__ agg,
                                                     const float* __restrict__ self_feat,
                                                     const float* __restrict__ dis,
                                                     const float* __restrict__ Wd,
                                                     const float* __restrict__ bd,
                                                     unsigned short* __restrict__ out) {
    __shared__ float rows[4 * 64];
    __shared__ float sW[64 * 64];
    const int tid = threadIdx.x;
    {
        const float4* w4 = (const float4*)Wd;
        float4* sw4 = (float4*)sW;
        for (int i = tid; i < 1024; i += 256) sw4[i] = w4[i];
    }
    const int r = tid >> 6, c = tid & 63;
    const long i = (long)blockIdx.x * 4 + r;
    const float dsi = dis[i];
    rows[r * 64 + c] = agg[i * 64 + c] + self_feat[i * 64 + c] * dsi * dsi;
    __syncthreads();
    float acc = 0.f;
    for (int k = 0; k < 64; k += 4) {
        const float4 a = *(const float4*)&rows[r * 64 + k];
        acc += a.x * sW[(k+0)*64+c] + a.y * sW[(k+1)*64+c]
             + a.z * sW[(k+2)*64+c] + a.w * sW[(k+3)*64+c];
    }
    out[i * 64 + c] = f2bf(fmaxf(acc + bd[c], 0.f));
}

// ----- K9-prep: WaT[n][k'] = bf16(Wa[k][n]), k' = d*4+part, k = part*64+d -----
__global__ void k_prep_wa(const float* __restrict__ Wa, unsigned short* __restrict__ WaT) {
    const int idx = blockIdx.x * 256 + threadIdx.x;   // 0..16383
    const int n = idx >> 8, kp = idx & 255;
    const int d = kp >> 2, part = kp & 3;
    WaT[idx] = f2bf(Wa[(part * 64 + d) * 64 + n]);
}

// ---------------- K9: edge MLP via MFMA, A-frag built in registers ----------
// 4 waves/block; wave = 2 M-tiles x 16 edges; block = 128 edges; grid 5625.
// A-frag: lane (quad,l15) needs phi[edge=l15][k'=ks*32+quad*8..+7] which is
// dims {quad*2, quad*2+1} of bf16 rows u,v -> two 4B gathers per ks, zero LDS.
// B in LDS (32KB exactly), 16B groups XOR-swizzled by (row&7): per 16-lane
// phase 2 lanes/bank (free, m136).
__global__ __launch_bounds__(256, 4) void k_edge_mlp_mfma(
        const unsigned short* __restrict__ h2bf,
        const int* __restrict__ pos,
        const int* __restrict__ neg,
        const unsigned short* __restrict__ WaT,
        const float* __restrict__ ba,
        const float* __restrict__ Wb,
        const float* __restrict__ bb,
        const float* __restrict__ tau,
        double* __restrict__ recon_accum) {
    __shared__ unsigned short sWb[64 * 256];   // 32768 B, swizzled
    const int tid = threadIdx.x;
    const int w = tid >> 6, lane = tid & 63;
    const int l15 = lane & 15, quad = lane >> 4;

    for (int i = tid; i < 2048; i += 256) {
        const int n = i >> 5, g = i & 31;
        *(int4*)&sWb[n * 256 + ((g ^ (n & 7)) << 3)] =
            *(const int4*)&WaT[n * 256 + (g << 3)];
    }
    __syncthreads();

    float ban[4], wbn[4];
#pragma unroll
    for (int t = 0; t < 4; ++t) {
        ban[t] = ba[t * 16 + l15];
        wbn[t] = Wb[t * 16 + l15];
    }
    const float bb0 = bb[0];
    const float itau = 1.0f / fmaxf(tau[0], 1e-4f);

    const long ebase = (long)blockIdx.x * 128 + (long)w * 32;
    float lsum = 0.f;

    for (int mt = 0; mt < 2; ++mt) {
        const long j = ebase + mt * 16 + l15;   // this lane's edge (by l15)
        const int* up = (j < EP) ? (pos + j) : (neg + (j - EP));
        const int* vp = (j < EP) ? (pos + EP + j) : (neg + ENEG + (j - EP));
        const int u = *up, v = *vp;
        const unsigned short* ur = h2bf + (long)u * 64 + quad * 2;
        const unsigned short* vr = h2bf + (long)v * 64 + quad * 2;
        unsigned int huw[8], hvw[8];
#pragma unroll
        for (int ks = 0; ks < 8; ++ks) {
            huw[ks] = *(const unsigned int*)(ur + ks * 8);
            hvw[ks] = *(const unsigned int*)(vr + ks * 8);
        }
        f32x4 acc[4];
#pragma unroll
        for (int t = 0; t < 4; ++t) acc[t] = (f32x4){0.f, 0.f, 0.f, 0.f};
#pragma unroll
        for (int ks = 0; ks < 8; ++ks) {
            const unsigned hu = huw[ks], hv = hvw[ks];
            const float hu0 = __uint_as_float(hu << 16);
            const float hu1 = __uint_as_float(hu & 0xFFFF0000u);
            const float hv0 = __uint_as_float(hv << 16);
            const float hv1 = __uint_as_float(hv & 0xFFFF0000u);
            const float ad0 = fabsf(hu0 - hv0), ad1 = fabsf(hu1 - hv1);
            const float pr0 = hu0 * hv0,        pr1 = hu1 * hv1;
            union { unsigned u32[4]; bf16x8 v; } af;
            af.u32[0] = (hu & 0xFFFFu) | (hv << 16);            // hu(d0), hv(d0)
            af.u32[2] = (hu >> 16) | (hv & 0xFFFF0000u);        // hu(d1), hv(d1)
            {   // ad/pr packed bf16 (RNE)
                const __hip_bfloat162 p01 = __float22bfloat162_rn(float2{ad0, pr0});
                const __hip_bfloat162 p23 = __float22bfloat162_rn(float2{ad1, pr1});
                union { __hip_bfloat162 h; unsigned u; } c0, c1;
                c0.h = p01; c1.h = p23;
                af.u32[1] = c0.u;
                af.u32[3] = c1.u;
            }
            const int gbase = (ks << 2) + quad;
#pragma unroll
            for (int t = 0; t < 4; ++t) {
                const bf16x8 bfv = *(const bf16x8*)&sWb[(t * 16 + l15) * 256 +
                                                        ((gbase ^ (l15 & 7)) << 3)];
                acc[t] = __builtin_amdgcn_mfma_f32_16x16x32_bf16(af.v, bfv, acc[t], 0, 0, 0);
            }
        }
        // epilogue: relu(+ba)*Wb, reduce over n, logits (D row = quad*4+r)
#pragma unroll
        for (int r = 0; r < 4; ++r) {
            float s = 0.f;
#pragma unroll
            for (int t = 0; t < 4; ++t) s += fmaxf(acc[t][r] + ban[t], 0.f) * wbn[t];
            for (int o = 8; o > 0; o >>= 1) s += __shfl_xor(s, o, 64);
            if (l15 == 0) {
                const long je = ebase + mt * 16 + quad * 4 + r;
                const float logit = (s + bb0) * itau;
                lsum += (je < EP) ? 5.0f * logsigf(logit) : logsigf(-logit);
            }
        }
    }
    // lanes 0,16,32,48 hold partials -> lane 0; block-reduce via reused sWb
    lsum += __shfl_xor(lsum, 16, 64);
    lsum += __shfl_xor(lsum, 32, 64);
    __syncthreads();                 // everyone done reading sWb
    if (lane == 0) ((double*)sWb)[w] = (double)lsum;
    __syncthreads();
    if (tid == 0) {
        double* dr = (double*)sWb;
        atomicAdd(recon_accum, dr[0] + dr[1] + dr[2] + dr[3]);
    }
}

// ---------------- K10: finalize ----------------
__global__ void k_final(const double* __restrict__ accum, float* __restrict__ out) {
    if (threadIdx.x == 0) {
        const double recon = -accum[0] / (double)ETOT;
        const double kl = -0.5 * accum[1] / ((double)N_NODES * 64.0);
        out[0] = (float)(recon + kl);
        out[1] = (float)recon;
        out[2] = (float)kl;
    }
}

extern "C" void kernel_launch(void* const* d_in, const int* in_sizes, int n_in,
                              void* d_out, int out_size, void* d_ws, size_t ws_size,
                              hipStream_t stream) {
    const float* x   = (const float*)d_in[0];
    const float* eps = (const float*)d_in[1];
    const int* EI    = (const int*)d_in[2];   // [2, 240000]
    const int* pos   = (const int*)d_in[3];   // [2, 120000]
    const int* neg   = (const int*)d_in[4];   // [2, 600000]
    const float* W1  = (const float*)d_in[5];
    const float* b1  = (const float*)d_in[6];
    const float* g1  = (const float*)d_in[7];
    const float* bt1 = (const float*)d_in[8];
    const float* Wmu = (const float*)d_in[9];
    const float* bmu = (const float*)d_in[10];
    const float* Wlv = (const float*)d_in[11];
    const float* blv = (const float*)d_in[12];
    const float* Wd1 = (const float*)d_in[13];
    const float* bd1 = (const float*)d_in[14];
    const float* Wd2 = (const float*)d_in[15];
    const float* bd2 = (const float*)d_in[16];
    const float* Wa  = (const float*)d_in[17];
    const float* ba  = (const float*)d_in[18];
    const float* Wb  = (const float*)d_in[19];
    const float* bb  = (const float*)d_in[20];
    const float* tau = (const float*)d_in[21];

    const int* e_src = EI;
    const int* e_dst = EI + E2;
    const int* ps = pos;
    const int* pd = pos + EP;

    // workspace layout (floats). Region A is reused: m1 -> agg1 -> h2bf.
    float* ws = (float*)d_ws;
    float* m1   = ws;                 // [20000,256]  (A)
    float* agg1 = ws;                 //              (A, after m1 dead)
    unsigned short* h2bf = (unsigned short*)ws;  // [20000,64] bf16 (A, after agg1 dead)
    float* h1   = ws + 5120000;       // [20000,256]  (B)
    float* z    = ws + 10240000;      // [20000,64]
    float* dis  = ws + 11520000;      // [20000]
    float* aggz = ws + 11552768;      // [20000,64]
    float* hdec = ws + 12832768;      // [20000,64]
    float* aggh = ws + 14112768;      // [20000,64]
    double* accum = (double*)(ws + 15392768); // [0]=recon_sum [1]=kl_sum
    unsigned short* WaT = (unsigned short*)(ws + 15392776); // [64,256] bf16

    hipMemsetAsync(accum, 0, 16, stream);
    k_prep_wa<<<64, 256, 0, stream>>>(Wa, WaT);

    // encoder layer 1
    k_mm_xW1<<<2500, 256, 0, stream>>>(x, W1, m1);
    hipMemsetAsync(h1, 0, (size_t)5120000 * 4, stream);
    k_scatter256<<<E2 / 8, 256, 0, stream>>>(m1, h1, e_src, e_dst);
    k_ln_relu<<<5000, 256, 0, stream>>>(h1, b1, g1, bt1);

    // shared aggregation for mu/logvar, then z + kl
    hipMemsetAsync(agg1, 0, (size_t)5120000 * 4, stream);
    k_scatter256<<<E2 / 8, 256, 0, stream>>>(h1, agg1, e_src, e_dst);
    k_mulv<<<5000, 256, 0, stream>>>(agg1, Wmu, bmu, Wlv, blv, eps, z, accum + 1);

    // decoder normalization
    hipMemsetAsync(dis, 0, (size_t)N_NODES * 4, stream);
    k_deg<<<(EP + 255) / 256, 256, 0, stream>>>(pd, dis);
    k_dis<<<(N_NODES + 255) / 256, 256, 0, stream>>>(dis);

    // decoder layer 1
    hipMemsetAsync(aggz, 0, (size_t)1280000 * 4, stream);
    k_scatter_norm64<<<EP / 16, 256, 0, stream>>>(z, aggz, ps, pd, dis);
    k_dec_mm<<<5000, 256, 0, stream>>>(aggz, z, dis, Wd1, bd1, hdec);

    // decoder layer 2 -> bf16 h2 (only the edge MLP reads it)
    hipMemsetAsync(aggh, 0, (size_t)1280000 * 4, stream);
    k_scatter_norm64<<<EP / 16, 256, 0, stream>>>(hdec, aggh, ps, pd, dis);
    k_dec_mm_bf16<<<5000, 256, 0, stream>>>(aggh, hdec, dis, Wd2, bd2, h2bf);

    // edge MLP + loss (MFMA, register A-frags)
    k_edge_mlp_mfma<<<ETOT / 128, 256, 0, stream>>>(h2bf, pos, neg, WaT, ba, Wb, bb, tau, accum);
    k_final<<<1, 64, 0, stream>>>(accum, (float*)d_out);
}

// Round 4
// 928.137 us; speedup vs baseline: 1.4428x; 1.4428x over previous
//
#include <hip/hip_runtime.h>
#include <hip/hip_bf16.h>
#include <math.h>

#define N_NODES 20000
#define E2      240000     // directed edges (2E)
#define EP      120000     // positive edges
#define ENEG    600000     // negative edges
#define ETOT    720000     // EP + ENEG

typedef __attribute__((ext_vector_type(8))) short bf16x8;
typedef __attribute__((ext_vector_type(4))) float f32x4;

__device__ __forceinline__ float logsigf(float x) {
    return fminf(x, 0.0f) - log1pf(expf(-fabsf(x)));
}

__device__ __forceinline__ unsigned short f2bf(float f) {
    unsigned u = __float_as_uint(f);
    u += 0x7FFF + ((u >> 16) & 1);   // RNE
    return (unsigned short)(u >> 16);
}

// ---------------- K1: m1 = x @ W1   [20000,256] @ [256,256] ----------------
__global__ __launch_bounds__(256) void k_mm_xW1(const float* __restrict__ x,
                                                const float* __restrict__ W1,
                                                float* __restrict__ m1) {
    __shared__ float xl[8 * 256];
    const int tid = threadIdx.x;
    const long base = (long)blockIdx.x * 8 * 256;
    const float4* src = (const float4*)(x + base);
    float4* dst = (float4*)xl;
    for (int i = tid; i < 512; i += 256) dst[i] = src[i];
    __syncthreads();
    float acc[8] = {0.f,0.f,0.f,0.f,0.f,0.f,0.f,0.f};
    for (int k = 0; k < 256; k += 4) {
        const float w0 = W1[(k + 0) * 256 + tid];
        const float w1 = W1[(k + 1) * 256 + tid];
        const float w2 = W1[(k + 2) * 256 + tid];
        const float w3 = W1[(k + 3) * 256 + tid];
#pragma unroll
        for (int r = 0; r < 8; ++r) {
            const float4 xv = *(const float4*)&xl[r * 256 + k];
            acc[r] += xv.x * w0 + xv.y * w1 + xv.z * w2 + xv.w * w3;
        }
    }
#pragma unroll
    for (int r = 0; r < 8; ++r) m1[base + r * 256 + tid] = acc[r];
}

// ---------------- CSR build: histogram -> scan -> fill ----------------
__global__ void k_hist(const int* __restrict__ dsts, int* __restrict__ cnt, int nE) {
    const int e = blockIdx.x * 256 + threadIdx.x;
    if (e < nE) atomicAdd(&cnt[dsts[e]], 1);
}

// single-block exclusive scan over n counts; writes row_start (n+1) and cursor
// (cursor may alias cnt: each element is read before being overwritten).
__global__ __launch_bounds__(1024) void k_scan(const int* __restrict__ cnt,
                                               int* __restrict__ rs,
                                               int* __restrict__ cur, int n) {
    __shared__ int wexc[16];
    __shared__ int s_carry, s_tot;
    const int tid = threadIdx.x, lane = tid & 63, wid = tid >> 6;
    if (tid == 0) s_carry = 0;
    __syncthreads();
    for (int base = 0; base < n; base += 1024) {
        const int i = base + tid;
        const int v = (i < n) ? cnt[i] : 0;
        int x = v;
#pragma unroll
        for (int d = 1; d < 64; d <<= 1) {
            const int t = __shfl_up(x, d, 64);
            if (lane >= d) x += t;
        }
        if (lane == 63) wexc[wid] = x;
        __syncthreads();
        if (tid == 0) {
            int a = 0;
#pragma unroll
            for (int k = 0; k < 16; ++k) { const int t = wexc[k]; wexc[k] = a; a += t; }
            s_tot = a;
        }
        __syncthreads();
        const int excl = s_carry + wexc[wid] + x - v;
        if (i < n) { rs[i] = excl; cur[i] = excl; }
        __syncthreads();
        if (tid == 0) s_carry += s_tot;
        __syncthreads();
    }
    if (tid == 0) rs[n] = s_carry;
}

__global__ void k_fill(const int* __restrict__ srcs, const int* __restrict__ dsts,
                       int* __restrict__ cur, int* __restrict__ adj, int nE) {
    const int e = blockIdx.x * 256 + threadIdx.x;
    if (e < nE) {
        const int d = dsts[e];
        const int p = atomicAdd(&cur[d], 1);
        adj[p] = srcs[e];
    }
}

// dis[i] = rsqrt(deg_pos(i) + 1)  (degree incl self loop), from pos CSR rs
__global__ void k_dis(const int* __restrict__ rsP, float* __restrict__ dis) {
    const int i = blockIdx.x * 256 + threadIdx.x;
    if (i < N_NODES) dis[i] = rsqrtf((float)(rsP[i + 1] - rsP[i] + 1));
}

// ---- K2: h1 = relu(LN(segsum(m1[adj]) + b1)); gather per node (dim 256) ----
__global__ __launch_bounds__(256) void k_gather_ln(const float* __restrict__ m1,
                                                   const int* __restrict__ rs,
                                                   const int* __restrict__ adj,
                                                   const float* __restrict__ b1,
                                                   const float* __restrict__ g1,
                                                   const float* __restrict__ bt1,
                                                   float* __restrict__ h1) {
    const int wid = threadIdx.x >> 6, lane = threadIdx.x & 63;
    const int n = blockIdx.x * 4 + wid;
    const int beg = rs[n], end = rs[n + 1];
    float4 a0 = {0.f,0.f,0.f,0.f}, a1 = {0.f,0.f,0.f,0.f};
    int j = beg;
    for (; j + 1 < end; j += 2) {
        const int s0 = adj[j], s1 = adj[j + 1];
        const float4 u = *(const float4*)(m1 + (long)s0 * 256 + lane * 4);
        const float4 v = *(const float4*)(m1 + (long)s1 * 256 + lane * 4);
        a0.x += u.x; a0.y += u.y; a0.z += u.z; a0.w += u.w;
        a1.x += v.x; a1.y += v.y; a1.z += v.z; a1.w += v.w;
    }
    if (j < end) {
        const int s0 = adj[j];
        const float4 u = *(const float4*)(m1 + (long)s0 * 256 + lane * 4);
        a0.x += u.x; a0.y += u.y; a0.z += u.z; a0.w += u.w;
    }
    float4 v;
    const float4 b = *(const float4*)(b1 + lane * 4);
    v.x = a0.x + a1.x + b.x; v.y = a0.y + a1.y + b.y;
    v.z = a0.z + a1.z + b.z; v.w = a0.w + a1.w + b.w;
    float s  = v.x + v.y + v.z + v.w;
    float sq = v.x * v.x + v.y * v.y + v.z * v.z + v.w * v.w;
    for (int o = 32; o > 0; o >>= 1) {
        s  += __shfl_xor(s, o, 64);
        sq += __shfl_xor(sq, o, 64);
    }
    const float mean = s * (1.0f / 256.0f);
    const float var  = sq * (1.0f / 256.0f) - mean * mean;
    const float rsv = rsqrtf(var + 1e-5f);
    const float4 g  = *(const float4*)(g1 + lane * 4);
    const float4 bt = *(const float4*)(bt1 + lane * 4);
    float4 o4;
    o4.x = fmaxf((v.x - mean) * rsv * g.x + bt.x, 0.f);
    o4.y = fmaxf((v.y - mean) * rsv * g.y + bt.y, 0.f);
    o4.z = fmaxf((v.z - mean) * rsv * g.z + bt.z, 0.f);
    o4.w = fmaxf((v.w - mean) * rsv * g.w + bt.w, 0.f);
    *(float4*)(h1 + (long)n * 256 + lane * 4) = o4;
}

// ---- K4: agg1 = segsum(h1[adj]); gather per node (dim 256) ----
__global__ __launch_bounds__(256) void k_gather256(const float* __restrict__ feat,
                                                   const int* __restrict__ rs,
                                                   const int* __restrict__ adj,
                                                   float* __restrict__ out) {
    const int wid = threadIdx.x >> 6, lane = threadIdx.x & 63;
    const int n = blockIdx.x * 4 + wid;
    const int beg = rs[n], end = rs[n + 1];
    float4 a0 = {0.f,0.f,0.f,0.f}, a1 = {0.f,0.f,0.f,0.f};
    int j = beg;
    for (; j + 1 < end; j += 2) {
        const int s0 = adj[j], s1 = adj[j + 1];
        const float4 u = *(const float4*)(feat + (long)s0 * 256 + lane * 4);
        const float4 v = *(const float4*)(feat + (long)s1 * 256 + lane * 4);
        a0.x += u.x; a0.y += u.y; a0.z += u.z; a0.w += u.w;
        a1.x += v.x; a1.y += v.y; a1.z += v.z; a1.w += v.w;
    }
    if (j < end) {
        const int s0 = adj[j];
        const float4 u = *(const float4*)(feat + (long)s0 * 256 + lane * 4);
        a0.x += u.x; a0.y += u.y; a0.z += u.z; a0.w += u.w;
    }
    float4 o4;
    o4.x = a0.x + a1.x; o4.y = a0.y + a1.y;
    o4.z = a0.z + a1.z; o4.w = a0.w + a1.w;
    *(float4*)(out + (long)n * 256 + lane * 4) = o4;
}

// ------- K5: mu/logvar from agg1, z = mu + eps*exp(lv/2), kl partial -------
__global__ __launch_bounds__(256) void k_mulv(const float* __restrict__ agg1,
                                              const float* __restrict__ Wmu,
                                              const float* __restrict__ bmu,
                                              const float* __restrict__ Wlv,
                                              const float* __restrict__ blv,
                                              const float* __restrict__ eps,
                                              float* __restrict__ z,
                                              double* __restrict__ kl_accum) {
    __shared__ float rows[4 * 256];
    const int tid = threadIdx.x;
    const long base = (long)blockIdx.x * 4 * 256;
    ((float4*)rows)[tid] = ((const float4*)(agg1 + base))[tid];
    __syncthreads();
    const int r = tid >> 6;
    const int c = tid & 63;
    float amu = 0.f, alv = 0.f;
    for (int k = 0; k < 256; k += 4) {
        const float4 a = *(const float4*)&rows[r * 256 + k];
        amu += a.x * Wmu[(k+0)*64+c] + a.y * Wmu[(k+1)*64+c]
             + a.z * Wmu[(k+2)*64+c] + a.w * Wmu[(k+3)*64+c];
        alv += a.x * Wlv[(k+0)*64+c] + a.y * Wlv[(k+1)*64+c]
             + a.z * Wlv[(k+2)*64+c] + a.w * Wlv[(k+3)*64+c];
    }
    const float mu = amu + bmu[c];
    const float lv = alv + blv[c];
    const long i = (long)blockIdx.x * 4 + r;
    const float ev = eps[i * 64 + c];
    z[i * 64 + c] = mu + ev * expf(0.5f * lv);
    float term = 1.0f + lv - mu * mu - expf(lv);
    for (int o = 32; o > 0; o >>= 1) term += __shfl_xor(term, o, 64);
    if (c == 0) atomicAdd(kl_accum, (double)term);
}

// ---- K7a/K8a: normalized gather (dim 64) over pos CSR ----
// out[n] = dis[n] * sum_s feat[s]*dis[s]  (self term added in dec_mm)
__global__ __launch_bounds__(256) void k_gather_norm64(const float* __restrict__ feat,
                                                       const int* __restrict__ rs,
                                                       const int* __restrict__ adj,
                                                       const float* __restrict__ dis,
                                                       float* __restrict__ out) {
    const int wid = threadIdx.x >> 6, lane = threadIdx.x & 63;
    const int n = blockIdx.x * 4 + wid;
    const int beg = rs[n], end = rs[n + 1];
    float a0 = 0.f, a1 = 0.f;
    int j = beg;
    for (; j + 1 < end; j += 2) {
        const int s0 = adj[j], s1 = adj[j + 1];
        a0 += feat[(long)s0 * 64 + lane] * dis[s0];
        a1 += feat[(long)s1 * 64 + lane] * dis[s1];
    }
    if (j < end) {
        const int s0 = adj[j];
        a0 += feat[(long)s0 * 64 + lane] * dis[s0];
    }
    out[(long)n * 64 + lane] = (a0 + a1) * dis[n];
}

// --- K7b: hdec = relu((agg + self*dis^2) @ Wd + bd), fp32 out ---
__global__ __launch_bounds__(256) void k_dec_mm(const float* __restrict__ agg,
                                                const float* __restrict__ self_feat,
                                                const float* __restrict__ dis,
                                                const float* __restrict__ Wd,
                                                const float* __restrict__ bd,
                                                float* __restrict__ out) {
    __shared__ float rows[4 * 64];
    __shared__ float sW[64 * 64];
    const int tid = threadIdx.x;
    {
        const float4* w4 = (const float4*)Wd;
        float4* sw4 = (float4*)sW;
        for (int i = tid; i < 1024; i += 256) sw4[i] = w4[i];
    }
    const int r = tid >> 6, c = tid & 63;
    const long i = (long)blockIdx.x * 4 + r;
    const float dsi = dis[i];
    rows[r * 64 + c] = agg[i * 64 + c] + self_feat[i * 64 + c] * dsi * dsi;
    __syncthreads();
    float acc = 0.f;
    for (int k = 0; k < 64; k += 4) {
        const float4 a = *(const float4*)&rows[r * 64 + k];
        acc += a.x * sW[(k+0)*64+c] + a.y * sW[(k+1)*64+c]
             + a.z * sW[(k+2)*64+c] + a.w * sW[(k+3)*64+c];
    }
    out[i * 64 + c] = fmaxf(acc + bd[c], 0.f);
}

// --- K8b: h2bf = bf16(relu((agg + self*dis^2) @ Wd + bd)) ---
__global__ __launch_bounds__(256) void k_dec_mm_bf16(const float* __restrict__ agg,
                                                     const float* __restrict__ self_feat,
                                                     const float* __restrict__ dis,
                                                     const float* __restrict__ Wd,
                                                     const float* __restrict__ bd,
                                                     unsigned short* __restrict__ out) {
    __shared__ float rows[4 * 64];
    __shared__ float sW[64 * 64];
    const int tid = threadIdx.x;
    {
        const float4* w4 = (const float4*)Wd;
        float4* sw4 = (float4*)sW;
        for (int i = tid; i < 1024; i += 256) sw4[i] = w4[i];
    }
    const int r = tid >> 6, c = tid & 63;
    const long i = (long)blockIdx.x * 4 + r;
    const float dsi = dis[i];
    rows[r * 64 + c] = agg[i * 64 + c] + self_feat[i * 64 + c] * dsi * dsi;
    __syncthreads();
    float acc = 0.f;
    for (int k = 0; k < 64; k += 4) {
        const float4 a = *(const float4*)&rows[r * 64 + k];
        acc += a.x * sW[(k+0)*64+c] + a.y * sW[(k+1)*64+c]
             + a.z * sW[(k+2)*64+c] + a.w * sW[(k+3)*64+c];
    }
    out[i * 64 + c] = f2bf(fmaxf(acc + bd[c], 0.f));
}

// ----- K9-prep: WaT[n][k'] = bf16(Wa[k][n]), k' = d*4+part, k = part*64+d -----
__global__ void k_prep_wa(const float* __restrict__ Wa, unsigned short* __restrict__ WaT) {
    const int idx = blockIdx.x * 256 + threadIdx.x;   // 0..16383
    const int n = idx >> 8, kp = idx & 255;
    const int d = kp >> 2, part = kp & 3;
    WaT[idx] = f2bf(Wa[(part * 64 + d) * 64 + n]);
}

// ---------------- K9: edge MLP via MFMA ----------------
// 4 waves/block; wave = 2 M-tiles x 16 edges; block = 128 edges; grid 5625.
// Coalesced 128B bf16 row loads (edge indices are wave-uniform s_loads);
// phi staged per-wave in private sPhi (NO barrier in main loop); B in LDS
// 32KB XOR-swizzled.
__global__ __launch_bounds__(256) void k_edge_mlp_mfma(
        const unsigned short* __restrict__ h2bf,
        const int* __restrict__ pos,
        const int* __restrict__ neg,
        const unsigned short* __restrict__ WaT,
        const float* __restrict__ ba,
        const float* __restrict__ Wb,
        const float* __restrict__ bb,
        const float* __restrict__ tau,
        double* __restrict__ recon_accum) {
    __shared__ unsigned short sWb[64 * 256];     // 32768 B, swizzled
    __shared__ unsigned short sPhi[4][16 * 264]; // 33792 B, per-wave private
    __shared__ double sRed[4];
    const int tid = threadIdx.x;
    const int w = tid >> 6, lane = tid & 63;
    const int l15 = lane & 15, quad = lane >> 4;

    for (int i = tid; i < 2048; i += 256) {
        const int n = i >> 5, g = i & 31;
        *(int4*)&sWb[n * 256 + ((g ^ (n & 7)) << 3)] =
            *(const int4*)&WaT[n * 256 + (g << 3)];
    }
    __syncthreads();

    float ban[4], wbn[4];
#pragma unroll
    for (int t = 0; t < 4; ++t) {
        ban[t] = ba[t * 16 + l15];
        wbn[t] = Wb[t * 16 + l15];
    }
    const float bb0 = bb[0];
    const float itau = 1.0f / fmaxf(tau[0], 1e-4f);

    const long ebase = (long)blockIdx.x * 128 + (long)w * 32;
    float lsum = 0.f;

    for (int mt = 0; mt < 2; ++mt) {
        const long e0 = ebase + mt * 16;
        // fill phi tile: edge indices wave-uniform -> s_load; rows coalesced
#pragma unroll
        for (int m = 0; m < 16; ++m) {
            const long j = e0 + m;
            int u, v;
            if (j < EP) { u = pos[j]; v = pos[EP + j]; }
            else        { u = neg[j - EP]; v = neg[ENEG + (j - EP)]; }
            const unsigned hu = h2bf[(long)u * 64 + lane];
            const unsigned hv = h2bf[(long)v * 64 + lane];
            const float fu = __uint_as_float(hu << 16);
            const float fv = __uint_as_float(hv << 16);
            const float ad = fabsf(fu - fv);
            const float pr = fu * fv;
            union { unsigned u32[2]; unsigned long long ll; } pk;
            pk.u32[0] = hu | (hv << 16);                        // k'=d*4+{0,1}
            {
                const __hip_bfloat162 p = __float22bfloat162_rn(float2{ad, pr});
                union { __hip_bfloat162 h; unsigned u; } cc; cc.h = p;
                pk.u32[1] = cc.u;                               // k'=d*4+{2,3}
            }
            *(unsigned long long*)&sPhi[w][m * 264 + lane * 4] = pk.ll;
        }
        // MFMA: D[16 edges][64 hid] = phi[16][256] @ Wa[256][64]
        f32x4 acc[4];
#pragma unroll
        for (int t = 0; t < 4; ++t) acc[t] = (f32x4){0.f, 0.f, 0.f, 0.f};
#pragma unroll
        for (int ks = 0; ks < 8; ++ks) {
            const bf16x8 af = *(const bf16x8*)&sPhi[w][l15 * 264 + ks * 32 + quad * 8];
            const int gbase = (ks << 2) + quad;
#pragma unroll
            for (int t = 0; t < 4; ++t) {
                const bf16x8 bfv = *(const bf16x8*)&sWb[(t * 16 + l15) * 256 +
                                                        ((gbase ^ (l15 & 7)) << 3)];
                acc[t] = __builtin_amdgcn_mfma_f32_16x16x32_bf16(af, bfv, acc[t], 0, 0, 0);
            }
        }
        // epilogue: relu(+ba)*Wb, reduce over n, logits (D row = quad*4+r)
#pragma unroll
        for (int r = 0; r < 4; ++r) {
            float s = 0.f;
#pragma unroll
            for (int t = 0; t < 4; ++t) s += fmaxf(acc[t][r] + ban[t], 0.f) * wbn[t];
            for (int o = 8; o > 0; o >>= 1) s += __shfl_xor(s, o, 64);
            if (l15 == 0) {
                const long je = e0 + quad * 4 + r;
                const float logit = (s + bb0) * itau;
                lsum += (je < EP) ? 5.0f * logsigf(logit) : logsigf(-logit);
            }
        }
    }
    lsum += __shfl_xor(lsum, 16, 64);
    lsum += __shfl_xor(lsum, 32, 64);
    if (lane == 0) sRed[w] = (double)lsum;
    __syncthreads();
    if (tid == 0) atomicAdd(recon_accum, sRed[0] + sRed[1] + sRed[2] + sRed[3]);
}

// ---------------- K10: finalize ----------------
__global__ void k_final(const double* __restrict__ accum, float* __restrict__ out) {
    if (threadIdx.x == 0) {
        const double recon = -accum[0] / (double)ETOT;
        const double kl = -0.5 * accum[1] / ((double)N_NODES * 64.0);
        out[0] = (float)(recon + kl);
        out[1] = (float)recon;
        out[2] = (float)kl;
    }
}

extern "C" void kernel_launch(void* const* d_in, const int* in_sizes, int n_in,
                              void* d_out, int out_size, void* d_ws, size_t ws_size,
                              hipStream_t stream) {
    const float* x   = (const float*)d_in[0];
    const float* eps = (const float*)d_in[1];
    const int* EI    = (const int*)d_in[2];   // [2, 240000]
    const int* pos   = (const int*)d_in[3];   // [2, 120000]
    const int* neg   = (const int*)d_in[4];   // [2, 600000]
    const float* W1  = (const float*)d_in[5];
    const float* b1  = (const float*)d_in[6];
    const float* g1  = (const float*)d_in[7];
    const float* bt1 = (const float*)d_in[8];
    const float* Wmu = (const float*)d_in[9];
    const float* bmu = (const float*)d_in[10];
    const float* Wlv = (const float*)d_in[11];
    const float* blv = (const float*)d_in[12];
    const float* Wd1 = (const float*)d_in[13];
    const float* bd1 = (const float*)d_in[14];
    const float* Wd2 = (const float*)d_in[15];
    const float* bd2 = (const float*)d_in[16];
    const float* Wa  = (const float*)d_in[17];
    const float* ba  = (const float*)d_in[18];
    const float* Wb  = (const float*)d_in[19];
    const float* bb  = (const float*)d_in[20];
    const float* tau = (const float*)d_in[21];

    const int* e_src = EI;
    const int* e_dst = EI + E2;
    const int* ps = pos;
    const int* pd = pos + EP;

    // ---- workspace layout (float units) ----
    float* ws = (float*)d_ws;
    float* m1    = ws;                        // [20000,256]  region A
    float* agg1  = ws;                        // A (after m1 dead)
    float* aggz  = ws;                        // A (after agg1 dead)
    float* hdec  = ws + 1280000;              // A
    float* aggh  = ws + 2560000;              // A
    unsigned short* h2bf = (unsigned short*)(ws + 3840000);  // A, bf16 [20000,64]
    float* h1    = ws + 5120000;              // [20000,256]  region B
    float* z     = ws + 10240000;             // [20000,64]
    float* dis   = ws + 11520000;             // [20000]
    double* accum = (double*)(ws + 11540000); // 2 doubles (8B-aligned)
    unsigned short* WaT = (unsigned short*)(ws + 11540004); // [64,256] bf16 (16B-aligned)
    int* cntA = (int*)(ws + 11548200);        // [20000] counts -> cursor
    int* rsA  = (int*)(ws + 11568200);        // [20001]
    int* adjA = (int*)(ws + 11588204);        // [240000]
    int* cntP = (int*)(ws + 11828204);        // [20000]
    int* rsP  = (int*)(ws + 11848204);        // [20001]
    int* adjP = (int*)(ws + 11868208);        // [120000]

    hipMemsetAsync(accum, 0, 16, stream);
    hipMemsetAsync(cntA, 0, N_NODES * 4, stream);
    hipMemsetAsync(cntP, 0, N_NODES * 4, stream);
    k_prep_wa<<<64, 256, 0, stream>>>(Wa, WaT);

    // CSR for undirected message graph (dst <- src over edge_index)
    k_hist<<<(E2 + 255) / 256, 256, 0, stream>>>(e_dst, cntA, E2);
    k_scan<<<1, 1024, 0, stream>>>(cntA, rsA, cntA, N_NODES);
    k_fill<<<(E2 + 255) / 256, 256, 0, stream>>>(e_src, e_dst, cntA, adjA, E2);

    // CSR for positive-edge decoder graph (pd <- ps) + dis
    k_hist<<<(EP + 255) / 256, 256, 0, stream>>>(pd, cntP, EP);
    k_scan<<<1, 1024, 0, stream>>>(cntP, rsP, cntP, N_NODES);
    k_fill<<<(EP + 255) / 256, 256, 0, stream>>>(ps, pd, cntP, adjP, EP);
    k_dis<<<(N_NODES + 255) / 256, 256, 0, stream>>>(rsP, dis);

    // encoder layer 1 (matmul, then fused gather+LN+relu)
    k_mm_xW1<<<2500, 256, 0, stream>>>(x, W1, m1);
    k_gather_ln<<<5000, 256, 0, stream>>>(m1, rsA, adjA, b1, g1, bt1, h1);

    // shared aggregation for mu/logvar, then z + kl
    k_gather256<<<5000, 256, 0, stream>>>(h1, rsA, adjA, agg1);
    k_mulv<<<5000, 256, 0, stream>>>(agg1, Wmu, bmu, Wlv, blv, eps, z, accum + 1);

    // decoder layer 1
    k_gather_norm64<<<5000, 256, 0, stream>>>(z, rsP, adjP, dis, aggz);
    k_dec_mm<<<5000, 256, 0, stream>>>(aggz, z, dis, Wd1, bd1, hdec);

    // decoder layer 2 -> bf16 h2
    k_gather_norm64<<<5000, 256, 0, stream>>>(hdec, rsP, adjP, dis, aggh);
    k_dec_mm_bf16<<<5000, 256, 0, stream>>>(aggh, hdec, dis, Wd2, bd2, h2bf);

    // edge MLP + loss (MFMA)
    k_edge_mlp_mfma<<<ETOT / 128, 256, 0, stream>>>(h2bf, pos, neg, WaT, ba, Wb, bb, tau, accum);
    k_final<<<1, 64, 0, stream>>>(accum, (float*)d_out);
}